// Round 4
// baseline (313.390 us; speedup 1.0000x reference)
//
#include <hip/hip_runtime.h>
#include <hip/hip_bf16.h>
#include <math.h>

#define T_AUDIO 441000
#define NH   2048
#define HOP  1024
#define NBINS 2049
#define NFRAMES 431
#define PAD  2048

// GEMM padded dims (bf16 buffers, zero-filled padding -> no guards in GEMM)
#define GP  2176   // padded g (M) = 17*128
#define KP  2112   // padded f (K) = 33*64
#define TPN 512    // padded frames per nc

#define NBLK 108   // istft blocks per njc (4 frames each)
#define SPAN 7168  // 4096 + 3*1024 samples per istft block

#define TWO_PI 6.2831853071795864769f

// LDS index padding for FFT buffers: +1 float2 per 16 -> breaks strided conflicts
#define PADI(i) ((i) + ((i) >> 4))

typedef __bf16 bf16_t;
typedef bf16_t bf16x8 __attribute__((ext_vector_type(8)));
typedef bf16_t bf16x4 __attribute__((ext_vector_type(4)));
typedef float f32x4 __attribute__((ext_vector_type(4)));
typedef _Float16 h16;
typedef h16 h16x4 __attribute__((ext_vector_type(4)));

__device__ __forceinline__ unsigned pack_bf2(float a, float b) {
    union { bf16_t h; unsigned short u; } ca, cb;
    ca.h = (bf16_t)a; cb.h = (bf16_t)b;
    return (unsigned)ca.u | ((unsigned)cb.u << 16);
}
__device__ __forceinline__ float2 unpack_bf2(unsigned v) {
    union { unsigned u; float f; } a, b;
    a.u = v << 16;
    b.u = v & 0xffff0000u;
    return make_float2(a.f, b.f);
}

__device__ __forceinline__ float2 cmul(float2 a, float2 b) {       // a*b
    return make_float2(a.x * b.x - a.y * b.y, a.x * b.y + a.y * b.x);
}
__device__ __forceinline__ float2 cmulc(float2 u, float2 w) {      // u*conj(w)
    return make_float2(u.x * w.x + u.y * w.y, u.y * w.x - u.x * w.y);
}

// twiddle table: tw[k] = (cos(2*pi*k/4096), sin(2*pi*k/4096)), k in [0,4096)
__global__ void k_tab(float2* __restrict__ tw) {
    int i = blockIdx.x * 256 + threadIdx.x;
    if (i < 4096) {
        float s, c;
        sincosf((float)i * (TWO_PI / 4096.0f), &s, &c);
        tw[i] = make_float2(c, s);
    }
}

// Stockham FFT len 2048: 5 radix-4 stages + 1 radix-2. Twiddles from global table.
// FWD=true: forward (W^-p). All LDS via PADI. 256 threads.
template<bool FWD>
__device__ float2* fft2048_r4(float2* x, float2* y, int tid,
                              const float2* __restrict__ tw) {
    const float sgn = FWD ? -1.0f : 1.0f;
    int n = 2048, ls = 0;
    #pragma unroll
    for (int st = 0; st < 5; st++) {
        int m = n >> 2, s = 1 << ls, fac = 4096 / n;
        #pragma unroll
        for (int it = 0; it < 2; it++) {
            int idx = tid + it * 256;
            int q = idx & (s - 1), p = idx >> ls;
            float2 a  = x[PADI(q + s * p)];
            float2 bb = x[PADI(q + s * (p + m))];
            float2 cc = x[PADI(q + s * (p + 2 * m))];
            float2 dd = x[PADI(q + s * (p + 3 * m))];
            float2 t0 = make_float2(a.x + cc.x, a.y + cc.y);
            float2 t1 = make_float2(a.x - cc.x, a.y - cc.y);
            float2 t2 = make_float2(bb.x + dd.x, bb.y + dd.y);
            float2 t3 = make_float2(bb.x - dd.x, bb.y - dd.y);
            float2 it3 = make_float2(-sgn * t3.y, sgn * t3.x);
            float2 u0 = make_float2(t0.x + t2.x, t0.y + t2.y);
            float2 u2 = make_float2(t0.x - t2.x, t0.y - t2.y);
            float2 u1 = make_float2(t1.x + it3.x, t1.y + it3.y);
            float2 u3 = make_float2(t1.x - it3.x, t1.y - it3.y);
            int e = p * fac;                    // max 3*e = 3070 < 4096
            float2 w1 = tw[e], w2 = tw[2 * e], w3 = tw[3 * e];
            int ob = q + s * 4 * p;
            y[PADI(ob)] = u0;
            if (FWD) {
                y[PADI(ob + s)]     = cmulc(u1, w1);
                y[PADI(ob + 2 * s)] = cmulc(u2, w2);
                y[PADI(ob + 3 * s)] = cmulc(u3, w3);
            } else {
                y[PADI(ob + s)]     = cmul(w1, u1);
                y[PADI(ob + 2 * s)] = cmul(w2, u2);
                y[PADI(ob + 3 * s)] = cmul(w3, u3);
            }
        }
        __syncthreads();
        float2* t = x; x = y; y = t;
        n = m; ls += 2;
    }
    #pragma unroll
    for (int it = 0; it < 4; it++) {
        int q = tid + it * 256;
        float2 a = x[PADI(q)], bb = x[PADI(q + 1024)];
        y[PADI(q)]        = make_float2(a.x + bb.x, a.y + bb.y);
        y[PADI(q + 1024)] = make_float2(a.x - bb.x, a.y - bb.y);
    }
    __syncthreads();
    return y;
}

// One block per (nc, frame): windowed 4096-pt rfft via packed 2048 complex FFT.
__global__ __launch_bounds__(256) void k_stft(const float* __restrict__ audio,
        bf16_t* __restrict__ Xb, unsigned* __restrict__ ph,
        const float2* __restrict__ tw) {
    __shared__ float2 bufA[2180];
    __shared__ float2 bufB[2180];
    int blk = blockIdx.x;
    int nc = blk / NFRAMES;
    int fr = blk - nc * NFRAMES;
    const float* a = audio + (size_t)nc * T_AUDIO;
    int tid = threadIdx.x;
    int base = fr * HOP - PAD;
    for (int m = tid; m < NH; m += 256) {
        int r0 = base + 2 * m;
        int r1 = r0 + 1;
        r0 = r0 < 0 ? -r0 : (r0 >= T_AUDIO ? 2 * T_AUDIO - 2 - r0 : r0);
        r1 = r1 < 0 ? -r1 : (r1 >= T_AUDIO ? 2 * T_AUDIO - 2 - r1 : r1);
        float4 tt = ((const float4*)tw)[m];   // (cos2m, sin2m, cos2m+1, sin2m+1)
        float x0 = a[r0] * (0.5f - 0.5f * tt.x);
        float x1 = a[r1] * (0.5f - 0.5f * tt.z);
        bufA[PADI(m)] = make_float2(x0, x1);
    }
    __syncthreads();
    float2* res = fft2048_r4<true>(bufA, bufB, tid, tw);
    size_t orow = ((size_t)nc * NFRAMES + fr) * KP;
    bf16_t* Xrow = Xb + ((size_t)nc * TPN + fr) * KP;
    for (int k = tid; k < NBINS; k += 256) {
        float2 Zk = res[PADI(k & 2047)];
        float2 Zm = res[PADI((2048 - k) & 2047)];
        float ex = 0.5f * (Zk.x + Zm.x), ey = 0.5f * (Zk.y - Zm.y);
        float ox = 0.5f * (Zk.y + Zm.y), oy = -0.5f * (Zk.x - Zm.x);
        float2 w = tw[k];
        float re = ex + w.x * ox + w.y * oy;
        float im = ey + w.x * oy - w.y * ox;
        float mag = sqrtf(re * re + im * im);
        float inv = 1.0f / (mag + 1e-10f);
        Xrow[k] = (bf16_t)mag;
        ph[orow + k] = pack_bf2(re * inv, im * inv);
    }
}

// W [4][2049][2049] fp32 -> Wb [4][GP][KP] bf16, zero-pad.
__global__ __launch_bounds__(256) void k_convW(const float* __restrict__ W,
        bf16_t* __restrict__ Wb) {
    size_t idx = (size_t)blockIdx.x * 256 + threadIdx.x;
    size_t total = (size_t)4 * GP * KP / 8;
    if (idx >= total) return;
    size_t e = idx * 8;
    int f0 = (int)(e % KP);
    size_t rem = e / KP;
    int g = (int)(rem % GP);
    int j = (int)(rem / GP);
    bf16x8 v = {};
    if (g < NBINS) {
        const float* src = W + ((size_t)j * NBINS + g) * NBINS;
        #pragma unroll
        for (int r = 0; r < 8; r++) {
            int f = f0 + r;
            v[r] = (bf16_t)(f < NBINS ? src[f] : 0.0f);
        }
    }
    *(bf16x8*)(Wb + e) = v;
}

// V[jnc][t][g] = relu(sum_f W[j][g][f]*X[nc][t][f] + b[j][g]), bf16 out.
// BM=128,BN=64,BK=64; swizzled LDS (zero bank conflicts, verified r3).
// 1D grid 2016 with XCD-grouping: 28 blocks sharing an A-panel -> same XCD.
__global__ __launch_bounds__(256) void k_gemm_mfma(const bf16_t* __restrict__ Wb,
        const float* __restrict__ bias, const bf16_t* __restrict__ Xb,
        bf16_t* __restrict__ V) {
    __shared__ bf16_t As[128 * 64];   // 16 KB
    __shared__ bf16_t Bs[64 * 64];    // 8 KB
    int id = blockIdx.x;
    int xcd = id & 7, nn = id >> 3;
    int G = xcd + 8 * (nn / 28);      // group = (j,g0); G%8 == xcd
    if (G >= 68) return;              // 72-group padding
    int m28 = nn % 28;
    int j  = G / 17;
    int g0 = (G % 17) * 128;
    int nc = m28 / 7;
    int t0 = (m28 % 7) * 64;
    const bf16_t* A = Wb + ((size_t)j * GP + g0) * KP;
    const bf16_t* B = Xb + ((size_t)nc * TPN + t0) * KP;
    int tid = threadIdx.x;
    int lane = tid & 63, wid = tid >> 6;
    int wm = wid >> 1, wn = wid & 1;

    const bf16_t* srcA[4];
    #pragma unroll
    for (int i = 0; i < 4; i++) {
        int s = i * 256 + tid;
        int r = s >> 3, cc = (s & 7) ^ (r & 7);
        srcA[i] = A + (size_t)r * KP + cc * 8;
    }
    const bf16_t* srcB[2];
    #pragma unroll
    for (int i = 0; i < 2; i++) {
        int s = i * 256 + tid;
        int r = s >> 3, cc = (s & 7) ^ (r & 7);
        srcB[i] = B + (size_t)r * KP + cc * 8;
    }

    int laneLo = lane & 15, laneHi = lane >> 4;
    int offA[4][2], offB[2][2];
    #pragma unroll
    for (int mm = 0; mm < 4; mm++) {
        int r = wm * 64 + mm * 16 + laneLo;
        #pragma unroll
        for (int kk = 0; kk < 2; kk++) {
            int c = kk * 4 + laneHi;
            offA[mm][kk] = r * 128 + ((c ^ (r & 7)) << 4);
        }
    }
    #pragma unroll
    for (int n = 0; n < 2; n++) {
        int r = wn * 32 + n * 16 + laneLo;
        #pragma unroll
        for (int kk = 0; kk < 2; kk++) {
            int c = kk * 4 + laneHi;
            offB[n][kk] = r * 128 + ((c ^ (r & 7)) << 4);
        }
    }

    f32x4 acc[4][2];
    #pragma unroll
    for (int mm = 0; mm < 4; mm++)
        #pragma unroll
        for (int n = 0; n < 2; n++)
            acc[mm][n] = (f32x4){0.f, 0.f, 0.f, 0.f};

    for (int k0 = 0; k0 < KP; k0 += 64) {
        #pragma unroll
        for (int i = 0; i < 4; i++)
            __builtin_amdgcn_global_load_lds(
                (const __attribute__((address_space(1))) void*)(srcA[i] + k0),
                (__attribute__((address_space(3))) void*)(As + (i * 256 + tid) * 8),
                16, 0, 0);
        #pragma unroll
        for (int i = 0; i < 2; i++)
            __builtin_amdgcn_global_load_lds(
                (const __attribute__((address_space(1))) void*)(srcB[i] + k0),
                (__attribute__((address_space(3))) void*)(Bs + (i * 256 + tid) * 8),
                16, 0, 0);
        __syncthreads();

        bf16x8 af[4][2], bfr[2][2];
        #pragma unroll
        for (int mm = 0; mm < 4; mm++)
            #pragma unroll
            for (int kk = 0; kk < 2; kk++)
                af[mm][kk] = *(const bf16x8*)((const char*)As + offA[mm][kk]);
        #pragma unroll
        for (int n = 0; n < 2; n++)
            #pragma unroll
            for (int kk = 0; kk < 2; kk++)
                bfr[n][kk] = *(const bf16x8*)((const char*)Bs + offB[n][kk]);
        #pragma unroll
        for (int mm = 0; mm < 4; mm++)
            #pragma unroll
            for (int n = 0; n < 2; n++)
                #pragma unroll
                for (int kk = 0; kk < 2; kk++)
                    acc[mm][n] = __builtin_amdgcn_mfma_f32_16x16x32_bf16(
                        af[mm][kk], bfr[n][kk], acc[mm][n], 0, 0, 0);
        __syncthreads();
    }

    int jnc = j * 4 + nc;
    int colT = laneLo;
    int rowB = laneHi * 4;
    #pragma unroll
    for (int n = 0; n < 2; n++) {
        int t = t0 + wn * 32 + n * 16 + colT;
        if (t >= NFRAMES) continue;
        size_t vrow = ((size_t)jnc * NFRAMES + t) * KP;
        #pragma unroll
        for (int mm = 0; mm < 4; mm++) {
            int g = g0 + wm * 64 + mm * 16 + rowB;
            if (g + 3 < NBINS) {
                bf16x4 o;
                #pragma unroll
                for (int r = 0; r < 4; r++)
                    o[r] = (bf16_t)fmaxf(acc[mm][n][r] + bias[j * NBINS + g + r], 0.0f);
                *(bf16x4*)(V + vrow + g) = o;
            } else {
                #pragma unroll
                for (int r = 0; r < 4; r++) {
                    int gg = g + r;
                    if (gg < NBINS)
                        V[vrow + gg] = (bf16_t)fmaxf(acc[mm][n][r] + bias[j * NBINS + gg], 0.0f);
                }
            }
        }
    }
}

// One block per (njc, 4 consecutive frames): Y=V*phase, irfft, window,
// overlap-add in LDS, write fp16 strip (no global read-modify-write).
__global__ __launch_bounds__(256) void k_istft(const bf16_t* __restrict__ V,
        const unsigned* __restrict__ ph, const float2* __restrict__ tw,
        h16* __restrict__ strips) {
    __shared__ float2 bufA[2180];
    __shared__ float2 bufB[2180];
    __shared__ float accS[SPAN];
    int b = blockIdx.x, njc = blockIdx.y;
    int n = njc >> 3, j = (njc >> 1) & 3, c = njc & 1;
    int nc = n * 2 + c;
    int jnc = j * 4 + nc;
    int tid = threadIdx.x;
    #pragma unroll
    for (int i = tid; i < SPAN / 4; i += 256)
        ((float4*)accS)[i] = make_float4(0.f, 0.f, 0.f, 0.f);

    for (int p = 0; p < 4; p++) {
        int fr = b * 4 + p;
        if (fr >= NFRAMES) break;
        __syncthreads();   // orders prev OLA / zeroing vs buffer refill
        size_t vrow = ((size_t)jnc * NFRAMES + fr) * KP;
        size_t prow = ((size_t)nc * NFRAMES + fr) * KP;
        for (int k = tid; k < NBINS; k += 256) {
            float v = (float)V[vrow + k];
            float2 pp = unpack_bf2(ph[prow + k]);
            bufA[PADI(k)] = make_float2(v * pp.x, v * pp.y);
        }
        __syncthreads();
        for (int k = tid; k < NH; k += 256) {
            float2 Yk = bufA[PADI(k)];
            float2 Ym = bufA[PADI(2048 - k)];
            float ex = 0.5f * (Yk.x + Ym.x), ey = 0.5f * (Yk.y - Ym.y);
            float wx = 0.5f * (Yk.x - Ym.x), wy = 0.5f * (Yk.y + Ym.y);
            float2 w = tw[k];
            float ox_ = w.x * wx - w.y * wy;
            float oy_ = w.x * wy + w.y * wx;
            bufB[PADI(k)] = make_float2(ex - oy_, ey + ox_);
        }
        __syncthreads();
        float2* res = fft2048_r4<false>(bufB, bufA, tid, tw);
        const float scale = 1.0f / 2048.0f;
        for (int m = tid; m < NH; m += 256) {
            float2 z = res[PADI(m)];
            float4 tt = ((const float4*)tw)[m];
            int o = p * 1024 + 2 * m;
            accS[o]     += z.x * scale * (0.5f - 0.5f * tt.x);
            accS[o + 1] += z.y * scale * (0.5f - 0.5f * tt.z);
        }
    }
    __syncthreads();
    h16* dst = strips + ((size_t)njc * NBLK + b) * SPAN;
    for (int i = tid; i < SPAN / 4; i += 256) {
        float4 v = ((float4*)accS)[i];
        h16x4 o = { (h16)v.x, (h16)v.y, (h16)v.z, (h16)v.w };
        *(h16x4*)(dst + i * 4) = o;
    }
}

// out[njc][t] = (strip[b1][o1] + strip[b1-1][o1+4096]) / wsq
__global__ __launch_bounds__(256) void k_final(const h16* __restrict__ strips,
        const float2* __restrict__ tw, float* __restrict__ out) {
    int gidx = blockIdx.x * 256 + threadIdx.x;
    int t = gidx * 2;
    if (t >= T_AUDIO) return;
    int njc = blockIdx.y;
    const h16* S = strips + (size_t)njc * NBLK * SPAN;
    float o[2];
    #pragma unroll
    for (int u = 0; u < 2; u++) {
        int tt = t + u;
        int q = tt + PAD;
        int b1 = q >> 12, o1 = q & 4095;
        float s = 0.f;
        if (b1 < NBLK) s += (float)S[b1 * SPAN + o1];
        if (b1 > 0 && o1 < SPAN - 4096) s += (float)S[(b1 - 1) * SPAN + o1 + 4096];
        float wsq;
        if (tt >= 1024 && tt <= 439295) {
            wsq = 1.5f;   // COLA interior: sum of 4 hann^2 at hop N/4
        } else {
            wsq = 0.f;
            int ib = q >> 10;
            #pragma unroll
            for (int d = 0; d < 4; d++) {
                int i = ib - d;
                if (i >= 0 && i < NFRAMES) {
                    int m = q - (i << 10);
                    float w = 0.5f - 0.5f * tw[m].x;
                    wsq += w * w;
                }
            }
            if (!(wsq > 1e-11f)) wsq = 1.f;
        }
        o[u] = s / wsq;
    }
    *(float2*)(out + (size_t)njc * T_AUDIO + t) = make_float2(o[0], o[1]);
}

extern "C" void kernel_launch(void* const* d_in, const int* in_sizes, int n_in,
                              void* d_out, int out_size, void* d_ws, size_t ws_size,
                              hipStream_t stream) {
    const float* audio = (const float*)d_in[0];
    const float* Wm    = (const float*)d_in[1];
    const float* bias  = (const float*)d_in[2];
    float* out = (float*)d_out;
    char* ws = (char*)d_ws;

    size_t szWb  = (size_t)4 * GP * KP * sizeof(bf16_t);        // 36.8 MB
    size_t szXb  = (size_t)4 * TPN * KP * sizeof(bf16_t);       //  8.7 MB
    size_t szPh  = (size_t)4 * NFRAMES * KP * sizeof(unsigned); // 14.6 MB
    size_t szV   = (size_t)16 * NFRAMES * KP * sizeof(bf16_t);  // 29.1 MB
    size_t szStr = (size_t)16 * NBLK * SPAN * sizeof(h16);      // 24.8 MB
    size_t szTw  = (size_t)4096 * sizeof(float2);               // 32 KB

    bf16_t*   Wb    = (bf16_t*)ws;   ws += szWb;
    bf16_t*   Xb    = (bf16_t*)ws;   ws += szXb;
    unsigned* ph    = (unsigned*)ws; ws += szPh;
    bf16_t*   V     = (bf16_t*)ws;   ws += szV;
    h16*      strips= (h16*)ws;      ws += szStr;
    float2*   tw    = (float2*)ws;   ws += szTw;
    if ((size_t)(ws - (char*)d_ws) > ws_size) return;

    hipMemsetAsync(Xb, 0, szXb, stream);

    k_tab<<<dim3(16), 256, 0, stream>>>(tw);
    k_convW<<<dim3((unsigned)((4ull * GP * KP / 8 + 255) / 256)), 256, 0, stream>>>(Wm, Wb);
    k_stft<<<dim3(4 * NFRAMES), 256, 0, stream>>>(audio, Xb, ph, tw);
    k_gemm_mfma<<<dim3(2016), 256, 0, stream>>>(Wb, bias, Xb, V);
    k_istft<<<dim3(NBLK, 16), 256, 0, stream>>>(V, ph, tw, strips);
    k_final<<<dim3((T_AUDIO / 2 + 255) / 256, 16), 256, 0, stream>>>(strips, tw, out);
}

// Round 5
// 255.413 us; speedup vs baseline: 1.2270x; 1.2270x over previous
//
#include <hip/hip_runtime.h>
#include <hip/hip_bf16.h>
#include <math.h>

#define T_AUDIO 441000
#define NH   2048
#define HOP  1024
#define NBINS 2049
#define NFRAMES 431
#define PAD  2048

// GEMM padded dims (bf16 buffers, zero-filled padding -> no guards in GEMM)
#define GP  2176   // padded g (M) = 17*128
#define KP  2112   // padded f (K) = 33*64
#define TPN 512    // padded frames per nc

#define NBLK 108   // istft blocks per njc (4 frames each)
#define SPAN 7168  // 4096 + 3*1024 samples per istft block

#define TWO_PI 6.2831853071795864769f

// LDS index padding for FFT buffers: +1 float2 per 16
#define PADI(i) ((i) + ((i) >> 4))

typedef __bf16 bf16_t;
typedef bf16_t bf16x8 __attribute__((ext_vector_type(8)));
typedef bf16_t bf16x4 __attribute__((ext_vector_type(4)));
typedef float f32x4 __attribute__((ext_vector_type(4)));
typedef _Float16 h16;
typedef h16 h16x4 __attribute__((ext_vector_type(4)));

__device__ __forceinline__ unsigned pack_bf2(float a, float b) {
    union { bf16_t h; unsigned short u; } ca, cb;
    ca.h = (bf16_t)a; cb.h = (bf16_t)b;
    return (unsigned)ca.u | ((unsigned)cb.u << 16);
}
__device__ __forceinline__ float2 unpack_bf2(unsigned v) {
    union { unsigned u; float f; } a, b;
    a.u = v << 16;
    b.u = v & 0xffff0000u;
    return make_float2(a.f, b.f);
}

__device__ __forceinline__ float2 cadd(float2 a, float2 b) { return make_float2(a.x + b.x, a.y + b.y); }
__device__ __forceinline__ float2 csub(float2 a, float2 b) { return make_float2(a.x - b.x, a.y - b.y); }
__device__ __forceinline__ float2 cmul(float2 a, float2 b) {       // a*b
    return make_float2(a.x * b.x - a.y * b.y, a.x * b.y + a.y * b.x);
}
__device__ __forceinline__ float2 cmulc(float2 u, float2 w) {      // u*conj(w)
    return make_float2(u.x * w.x + u.y * w.y, u.y * w.x - u.x * w.y);
}

// twiddle table: tw[k] = (cos(2*pi*k/4096), sin(2*pi*k/4096))
__global__ void k_tab(float2* __restrict__ tw) {
    int i = blockIdx.x * 256 + threadIdx.x;
    if (i < 4096) {
        float s, c;
        sincosf((float)i * (TWO_PI / 4096.0f), &s, &c);
        tw[i] = make_float2(c, s);
    }
}

// In-place Stockham FFT len 2048 in ONE LDS buffer: 3 radix-8 register sweeps
// + 1 dual radix-4 sweep. 256 threads; reads always x[PADI(tid+256k)] (conflict
// free). Ends with a barrier; result in natural order in x.
template<bool FWD>
__device__ __forceinline__ void fft2048_reg8(float2* x, int tid,
                                             const float2* __restrict__ tw) {
    const float sgn = FWD ? -1.0f : 1.0f;
    const float R2 = 0.70710678118654752440f;
    int s = 1, ls = 0, fac = 2;
    #pragma unroll
    for (int st = 0; st < 3; st++) {
        int q = tid & (s - 1);
        int p = tid >> ls;
        int e = p * fac;
        float2 w[7];
        #pragma unroll
        for (int k = 0; k < 7; k++) w[k] = tw[e * (k + 1)];
        float2 v[8];
        #pragma unroll
        for (int k = 0; k < 8; k++) v[k] = x[PADI(tid + 256 * k)];
        __syncthreads();
        float2 s0 = cadd(v[0], v[4]), s1 = cadd(v[1], v[5]),
               s2 = cadd(v[2], v[6]), s3 = cadd(v[3], v[7]);
        float2 d0 = csub(v[0], v[4]), d1 = csub(v[1], v[5]),
               d2 = csub(v[2], v[6]), d3 = csub(v[3], v[7]);
        float2 X0, X1, X2, X3, X4, X5, X6, X7;
        {   // even outputs: DFT4(s0..s3)
            float2 t0 = cadd(s0, s2), t1 = csub(s0, s2);
            float2 t2 = cadd(s1, s3), t3 = csub(s1, s3);
            float2 it3 = make_float2(-sgn * t3.y, sgn * t3.x);
            X0 = cadd(t0, t2); X4 = csub(t0, t2);
            X2 = cadd(t1, it3); X6 = csub(t1, it3);
        }
        {   // odd outputs: DFT4(d_j * W8^{sgn*j})
            float2 e0 = d0;
            float2 e1 = make_float2(R2 * (d1.x - sgn * d1.y), R2 * (sgn * d1.x + d1.y));
            float2 e2 = make_float2(-sgn * d2.y, sgn * d2.x);
            float2 e3 = make_float2(-R2 * (d3.x + sgn * d3.y), R2 * (sgn * d3.x - d3.y));
            float2 t0 = cadd(e0, e2), t1 = csub(e0, e2);
            float2 t2 = cadd(e1, e3), t3 = csub(e1, e3);
            float2 it3 = make_float2(-sgn * t3.y, sgn * t3.x);
            X1 = cadd(t0, t2); X5 = csub(t0, t2);
            X3 = cadd(t1, it3); X7 = csub(t1, it3);
        }
        int ob = q + 8 * s * p;
        x[PADI(ob)] = X0;
        float2 XX[7] = {X1, X2, X3, X4, X5, X6, X7};
        #pragma unroll
        for (int k = 0; k < 7; k++) {
            float2 u = XX[k];
            x[PADI(ob + s * (k + 1))] = FWD ? cmulc(u, w[k]) : cmul(w[k], u);
        }
        __syncthreads();
        s <<= 3; ls += 3; fac <<= 3;
    }
    {   // final radix-4, s=512, butterflies q=tid and q=tid+256 (twiddle-free)
        float2 v[8];
        #pragma unroll
        for (int k = 0; k < 8; k++) v[k] = x[PADI(tid + 256 * k)];
        __syncthreads();
        #pragma unroll
        for (int h = 0; h < 2; h++) {
            float2 c0 = v[h], c1 = v[h + 2], c2 = v[h + 4], c3 = v[h + 6];
            float2 t0 = cadd(c0, c2), t1 = csub(c0, c2);
            float2 t2 = cadd(c1, c3), t3 = csub(c1, c3);
            float2 it3 = make_float2(-sgn * t3.y, sgn * t3.x);
            int base = tid + 256 * h;
            x[PADI(base)]        = cadd(t0, t2);
            x[PADI(base + 512)]  = cadd(t1, it3);
            x[PADI(base + 1024)] = csub(t0, t2);
            x[PADI(base + 1536)] = csub(t1, it3);
        }
        __syncthreads();
    }
}

// One block per (nc, frame): windowed 4096-pt rfft via packed 2048 complex FFT.
__global__ __launch_bounds__(256) void k_stft(const float* __restrict__ audio,
        bf16_t* __restrict__ Xb, unsigned* __restrict__ ph,
        const float2* __restrict__ tw) {
    __shared__ float2 buf[2176];
    int blk = blockIdx.x;
    int nc = blk / NFRAMES;
    int fr = blk - nc * NFRAMES;
    const float* a = audio + (size_t)nc * T_AUDIO;
    int tid = threadIdx.x;
    int base = fr * HOP - PAD;
    #pragma unroll
    for (int it = 0; it < 8; it++) {
        int m = tid + it * 256;
        int r0 = base + 2 * m;
        int r1 = r0 + 1;
        r0 = r0 < 0 ? -r0 : (r0 >= T_AUDIO ? 2 * T_AUDIO - 2 - r0 : r0);
        r1 = r1 < 0 ? -r1 : (r1 >= T_AUDIO ? 2 * T_AUDIO - 2 - r1 : r1);
        float4 tt = ((const float4*)tw)[m];
        float x0 = a[r0] * (0.5f - 0.5f * tt.x);
        float x1 = a[r1] * (0.5f - 0.5f * tt.z);
        buf[PADI(m)] = make_float2(x0, x1);
    }
    __syncthreads();
    fft2048_reg8<true>(buf, tid, tw);
    size_t orow = ((size_t)nc * NFRAMES + fr) * KP;
    bf16_t* Xrow = Xb + ((size_t)nc * TPN + fr) * KP;
    for (int k = tid; k < NBINS; k += 256) {
        float2 Zk = buf[PADI(k & 2047)];
        float2 Zm = buf[PADI((2048 - k) & 2047)];
        float ex = 0.5f * (Zk.x + Zm.x), ey = 0.5f * (Zk.y - Zm.y);
        float ox = 0.5f * (Zk.y + Zm.y), oy = -0.5f * (Zk.x - Zm.x);
        float2 w = tw[k];
        float re = ex + w.x * ox + w.y * oy;
        float im = ey + w.x * oy - w.y * ox;
        float mag = sqrtf(re * re + im * im);
        float inv = 1.0f / (mag + 1e-10f);
        Xrow[k] = (bf16_t)mag;
        ph[orow + k] = pack_bf2(re * inv, im * inv);
    }
}

// W [4][2049][2049] fp32 -> Wb [4][GP][KP] bf16, zero-pad.
__global__ __launch_bounds__(256) void k_convW(const float* __restrict__ W,
        bf16_t* __restrict__ Wb) {
    size_t idx = (size_t)blockIdx.x * 256 + threadIdx.x;
    size_t total = (size_t)4 * GP * KP / 8;
    if (idx >= total) return;
    size_t e = idx * 8;
    int f0 = (int)(e % KP);
    size_t rem = e / KP;
    int g = (int)(rem % GP);
    int j = (int)(rem / GP);
    bf16x8 v = {};
    if (g < NBINS) {
        const float* src = W + ((size_t)j * NBINS + g) * NBINS;
        #pragma unroll
        for (int r = 0; r < 8; r++) {
            int f = f0 + r;
            v[r] = (bf16_t)(f < NBINS ? src[f] : 0.0f);
        }
    }
    *(bf16x8*)(Wb + e) = v;
}

// V[jnc][t][g] = relu(sum_f W[j][g][f]*X[nc][t][f] + b[j][g]), bf16 out.
// BM=128,BN=64,BK=64; swizzled LDS (0 bank conflicts); XCD-grouped 1D grid.
__global__ __launch_bounds__(256) void k_gemm_mfma(const bf16_t* __restrict__ Wb,
        const float* __restrict__ bias, const bf16_t* __restrict__ Xb,
        bf16_t* __restrict__ V) {
    __shared__ bf16_t As[128 * 64];
    __shared__ bf16_t Bs[64 * 64];
    int id = blockIdx.x;
    int xcd = id & 7, nn = id >> 3;
    int G = xcd + 8 * (nn / 28);
    if (G >= 68) return;
    int m28 = nn % 28;
    int j  = G / 17;
    int g0 = (G % 17) * 128;
    int nc = m28 / 7;
    int t0 = (m28 % 7) * 64;
    const bf16_t* A = Wb + ((size_t)j * GP + g0) * KP;
    const bf16_t* B = Xb + ((size_t)nc * TPN + t0) * KP;
    int tid = threadIdx.x;
    int lane = tid & 63, wid = tid >> 6;
    int wm = wid >> 1, wn = wid & 1;

    const bf16_t* srcA[4];
    #pragma unroll
    for (int i = 0; i < 4; i++) {
        int s = i * 256 + tid;
        int r = s >> 3, cc = (s & 7) ^ (r & 7);
        srcA[i] = A + (size_t)r * KP + cc * 8;
    }
    const bf16_t* srcB[2];
    #pragma unroll
    for (int i = 0; i < 2; i++) {
        int s = i * 256 + tid;
        int r = s >> 3, cc = (s & 7) ^ (r & 7);
        srcB[i] = B + (size_t)r * KP + cc * 8;
    }

    int laneLo = lane & 15, laneHi = lane >> 4;
    int offA[4][2], offB[2][2];
    #pragma unroll
    for (int mm = 0; mm < 4; mm++) {
        int r = wm * 64 + mm * 16 + laneLo;
        #pragma unroll
        for (int kk = 0; kk < 2; kk++) {
            int c = kk * 4 + laneHi;
            offA[mm][kk] = r * 128 + ((c ^ (r & 7)) << 4);
        }
    }
    #pragma unroll
    for (int n = 0; n < 2; n++) {
        int r = wn * 32 + n * 16 + laneLo;
        #pragma unroll
        for (int kk = 0; kk < 2; kk++) {
            int c = kk * 4 + laneHi;
            offB[n][kk] = r * 128 + ((c ^ (r & 7)) << 4);
        }
    }

    f32x4 acc[4][2];
    #pragma unroll
    for (int mm = 0; mm < 4; mm++)
        #pragma unroll
        for (int n = 0; n < 2; n++)
            acc[mm][n] = (f32x4){0.f, 0.f, 0.f, 0.f};

    for (int k0 = 0; k0 < KP; k0 += 64) {
        #pragma unroll
        for (int i = 0; i < 4; i++)
            __builtin_amdgcn_global_load_lds(
                (const __attribute__((address_space(1))) void*)(srcA[i] + k0),
                (__attribute__((address_space(3))) void*)(As + (i * 256 + tid) * 8),
                16, 0, 0);
        #pragma unroll
        for (int i = 0; i < 2; i++)
            __builtin_amdgcn_global_load_lds(
                (const __attribute__((address_space(1))) void*)(srcB[i] + k0),
                (__attribute__((address_space(3))) void*)(Bs + (i * 256 + tid) * 8),
                16, 0, 0);
        __syncthreads();

        bf16x8 af[4][2], bfr[2][2];
        #pragma unroll
        for (int mm = 0; mm < 4; mm++)
            #pragma unroll
            for (int kk = 0; kk < 2; kk++)
                af[mm][kk] = *(const bf16x8*)((const char*)As + offA[mm][kk]);
        #pragma unroll
        for (int n = 0; n < 2; n++)
            #pragma unroll
            for (int kk = 0; kk < 2; kk++)
                bfr[n][kk] = *(const bf16x8*)((const char*)Bs + offB[n][kk]);
        #pragma unroll
        for (int mm = 0; mm < 4; mm++)
            #pragma unroll
            for (int n = 0; n < 2; n++)
                #pragma unroll
                for (int kk = 0; kk < 2; kk++)
                    acc[mm][n] = __builtin_amdgcn_mfma_f32_16x16x32_bf16(
                        af[mm][kk], bfr[n][kk], acc[mm][n], 0, 0, 0);
        __syncthreads();
    }

    int jnc = j * 4 + nc;
    int colT = laneLo;
    int rowB = laneHi * 4;
    #pragma unroll
    for (int n = 0; n < 2; n++) {
        int t = t0 + wn * 32 + n * 16 + colT;
        if (t >= NFRAMES) continue;
        size_t vrow = ((size_t)jnc * NFRAMES + t) * KP;
        #pragma unroll
        for (int mm = 0; mm < 4; mm++) {
            int g = g0 + wm * 64 + mm * 16 + rowB;
            if (g + 3 < NBINS) {
                bf16x4 o;
                #pragma unroll
                for (int r = 0; r < 4; r++)
                    o[r] = (bf16_t)fmaxf(acc[mm][n][r] + bias[j * NBINS + g + r], 0.0f);
                *(bf16x4*)(V + vrow + g) = o;
            } else {
                #pragma unroll
                for (int r = 0; r < 4; r++) {
                    int gg = g + r;
                    if (gg < NBINS)
                        V[vrow + gg] = (bf16_t)fmaxf(acc[mm][n][r] + bias[j * NBINS + gg], 0.0f);
                }
            }
        }
    }
}

// One block per (njc, 4 frames): z-build direct from global V*phase, in-place
// iFFT (single 17.4KB buffer), window+OLA into LDS accS, fp16 strip out.
__global__ __launch_bounds__(256) void k_istft(const bf16_t* __restrict__ V,
        const unsigned* __restrict__ ph, const float2* __restrict__ tw,
        h16* __restrict__ strips) {
    __shared__ float2 buf[2176];
    __shared__ float accS[SPAN];
    int b = blockIdx.x, njc = blockIdx.y;
    int n = njc >> 3, j = (njc >> 1) & 3, c = njc & 1;
    int nc = n * 2 + c;
    int jnc = j * 4 + nc;
    int tid = threadIdx.x;
    #pragma unroll
    for (int i = tid; i < SPAN / 4; i += 256)
        ((float4*)accS)[i] = make_float4(0.f, 0.f, 0.f, 0.f);

    for (int p = 0; p < 4; p++) {
        int fr = b * 4 + p;
        if (fr >= NFRAMES) break;
        size_t vrow = ((size_t)jnc * NFRAMES + fr) * KP;
        size_t prow = ((size_t)nc * NFRAMES + fr) * KP;
        // build z directly: z[k] = E_k + i*e^{ia_k}*O_k from Y[k], Y[2048-k]
        #pragma unroll
        for (int it = 0; it < 8; it++) {
            int k = tid + it * 256;
            int km = 2048 - k;
            float vk = (float)V[vrow + k];
            float2 pk = unpack_bf2(ph[prow + k]);
            float vm = (float)V[vrow + km];
            float2 pm = unpack_bf2(ph[prow + km]);
            float2 Yk = make_float2(vk * pk.x, vk * pk.y);
            float2 Ym = make_float2(vm * pm.x, vm * pm.y);
            float ex = 0.5f * (Yk.x + Ym.x), ey = 0.5f * (Yk.y - Ym.y);
            float wx = 0.5f * (Yk.x - Ym.x), wy = 0.5f * (Yk.y + Ym.y);
            float2 w = tw[k];
            float ox_ = w.x * wx - w.y * wy;
            float oy_ = w.x * wy + w.y * wx;
            buf[PADI(k)] = make_float2(ex - oy_, ey + ox_);
        }
        __syncthreads();
        fft2048_reg8<false>(buf, tid, tw);
        const float scale = 1.0f / 2048.0f;
        #pragma unroll
        for (int it = 0; it < 8; it++) {
            int m = tid + it * 256;
            float2 z = buf[PADI(m)];
            float4 tt = ((const float4*)tw)[m];
            int o = p * 1024 + 2 * m;
            accS[o]     += z.x * scale * (0.5f - 0.5f * tt.x);
            accS[o + 1] += z.y * scale * (0.5f - 0.5f * tt.z);
        }
        __syncthreads();
    }
    h16* dst = strips + ((size_t)njc * NBLK + b) * SPAN;
    for (int i = tid; i < SPAN / 4; i += 256) {
        float4 v = ((float4*)accS)[i];
        h16x4 o = { (h16)v.x, (h16)v.y, (h16)v.z, (h16)v.w };
        *(h16x4*)(dst + i * 4) = o;
    }
}

// out[njc][t] = (strip[b1][o1] + strip[b1-1][o1+4096]) / wsq
__global__ __launch_bounds__(256) void k_final(const h16* __restrict__ strips,
        const float2* __restrict__ tw, float* __restrict__ out) {
    int gidx = blockIdx.x * 256 + threadIdx.x;
    int t = gidx * 2;
    if (t >= T_AUDIO) return;
    int njc = blockIdx.y;
    const h16* S = strips + (size_t)njc * NBLK * SPAN;
    float o[2];
    #pragma unroll
    for (int u = 0; u < 2; u++) {
        int tt = t + u;
        int q = tt + PAD;
        int b1 = q >> 12, o1 = q & 4095;
        float s = 0.f;
        if (b1 < NBLK) s += (float)S[b1 * SPAN + o1];
        if (b1 > 0 && o1 < SPAN - 4096) s += (float)S[(b1 - 1) * SPAN + o1 + 4096];
        float wsq;
        if (tt >= 1024 && tt <= 439295) {
            wsq = 1.5f;
        } else {
            wsq = 0.f;
            int ib = q >> 10;
            #pragma unroll
            for (int d = 0; d < 4; d++) {
                int i = ib - d;
                if (i >= 0 && i < NFRAMES) {
                    int m = q - (i << 10);
                    float w = 0.5f - 0.5f * tw[m].x;
                    wsq += w * w;
                }
            }
            if (!(wsq > 1e-11f)) wsq = 1.f;
        }
        o[u] = s / wsq;
    }
    *(float2*)(out + (size_t)njc * T_AUDIO + t) = make_float2(o[0], o[1]);
}

extern "C" void kernel_launch(void* const* d_in, const int* in_sizes, int n_in,
                              void* d_out, int out_size, void* d_ws, size_t ws_size,
                              hipStream_t stream) {
    const float* audio = (const float*)d_in[0];
    const float* Wm    = (const float*)d_in[1];
    const float* bias  = (const float*)d_in[2];
    float* out = (float*)d_out;
    char* ws = (char*)d_ws;

    size_t szWb  = (size_t)4 * GP * KP * sizeof(bf16_t);
    size_t szXb  = (size_t)4 * TPN * KP * sizeof(bf16_t);
    size_t szPh  = (size_t)4 * NFRAMES * KP * sizeof(unsigned);
    size_t szV   = (size_t)16 * NFRAMES * KP * sizeof(bf16_t);
    size_t szStr = (size_t)16 * NBLK * SPAN * sizeof(h16);
    size_t szTw  = (size_t)4096 * sizeof(float2);

    bf16_t*   Wb    = (bf16_t*)ws;   ws += szWb;
    bf16_t*   Xb    = (bf16_t*)ws;   ws += szXb;
    unsigned* ph    = (unsigned*)ws; ws += szPh;
    bf16_t*   V     = (bf16_t*)ws;   ws += szV;
    h16*      strips= (h16*)ws;      ws += szStr;
    float2*   tw    = (float2*)ws;   ws += szTw;
    if ((size_t)(ws - (char*)d_ws) > ws_size) return;

    hipMemsetAsync(Xb, 0, szXb, stream);

    k_tab<<<dim3(16), 256, 0, stream>>>(tw);
    k_convW<<<dim3((unsigned)((4ull * GP * KP / 8 + 255) / 256)), 256, 0, stream>>>(Wm, Wb);
    k_stft<<<dim3(4 * NFRAMES), 256, 0, stream>>>(audio, Xb, ph, tw);
    k_gemm_mfma<<<dim3(2016), 256, 0, stream>>>(Wb, bias, Xb, V);
    k_istft<<<dim3(NBLK, 16), 256, 0, stream>>>(V, ph, tw, strips);
    k_final<<<dim3((T_AUDIO / 2 + 255) / 256, 16), 256, 0, stream>>>(strips, tw, out);
}

// Round 6
// 255.140 us; speedup vs baseline: 1.2283x; 1.0011x over previous
//
#include <hip/hip_runtime.h>
#include <hip/hip_bf16.h>
#include <math.h>

#define T_AUDIO 441000
#define NH   2048
#define HOP  1024
#define NBINS 2049
#define NFRAMES 431
#define PAD  2048

// GEMM padded dims (bf16 buffers, zero-filled padding -> no guards in GEMM)
#define GP  2176   // padded g (M) = 17*128
#define KP  2112   // padded f (K) = 33*64
#define TPN 448    // padded frames per nc; merged N = 4*448 = 1792 = 14*128

#define NBLK 108   // istft blocks per njc (4 frames each)
#define SPAN 7168  // 4096 + 3*1024 samples per istft block

#define TWO_PI 6.2831853071795864769f

// LDS index padding for FFT buffers: +1 float2 per 16
#define PADI(i) ((i) + ((i) >> 4))

typedef __bf16 bf16_t;
typedef bf16_t bf16x8 __attribute__((ext_vector_type(8)));
typedef bf16_t bf16x4 __attribute__((ext_vector_type(4)));
typedef float f32x4 __attribute__((ext_vector_type(4)));
typedef _Float16 h16;
typedef h16 h16x4 __attribute__((ext_vector_type(4)));

__device__ __forceinline__ unsigned pack_bf2(float a, float b) {
    union { bf16_t h; unsigned short u; } ca, cb;
    ca.h = (bf16_t)a; cb.h = (bf16_t)b;
    return (unsigned)ca.u | ((unsigned)cb.u << 16);
}
__device__ __forceinline__ float2 unpack_bf2(unsigned v) {
    union { unsigned u; float f; } a, b;
    a.u = v << 16;
    b.u = v & 0xffff0000u;
    return make_float2(a.f, b.f);
}

__device__ __forceinline__ float2 cadd(float2 a, float2 b) { return make_float2(a.x + b.x, a.y + b.y); }
__device__ __forceinline__ float2 csub(float2 a, float2 b) { return make_float2(a.x - b.x, a.y - b.y); }
__device__ __forceinline__ float2 cmul(float2 a, float2 b) {       // a*b
    return make_float2(a.x * b.x - a.y * b.y, a.x * b.y + a.y * b.x);
}
__device__ __forceinline__ float2 cmulc(float2 u, float2 w) {      // u*conj(w)
    return make_float2(u.x * w.x + u.y * w.y, u.y * w.x - u.x * w.y);
}

// In-place Stockham FFT len 2048 in ONE LDS buffer: 3 radix-8 register sweeps
// + 1 dual radix-4 sweep. 256 threads; conflict-free reads. Ends with barrier.
template<bool FWD>
__device__ __forceinline__ void fft2048_reg8(float2* x, int tid,
                                             const float2* __restrict__ tw) {
    const float sgn = FWD ? -1.0f : 1.0f;
    const float R2 = 0.70710678118654752440f;
    int s = 1, ls = 0, fac = 2;
    #pragma unroll
    for (int st = 0; st < 3; st++) {
        int q = tid & (s - 1);
        int p = tid >> ls;
        int e = p * fac;
        float2 w[7];
        #pragma unroll
        for (int k = 0; k < 7; k++) w[k] = tw[e * (k + 1)];
        float2 v[8];
        #pragma unroll
        for (int k = 0; k < 8; k++) v[k] = x[PADI(tid + 256 * k)];
        __syncthreads();
        float2 s0 = cadd(v[0], v[4]), s1 = cadd(v[1], v[5]),
               s2 = cadd(v[2], v[6]), s3 = cadd(v[3], v[7]);
        float2 d0 = csub(v[0], v[4]), d1 = csub(v[1], v[5]),
               d2 = csub(v[2], v[6]), d3 = csub(v[3], v[7]);
        float2 X0, X1, X2, X3, X4, X5, X6, X7;
        {
            float2 t0 = cadd(s0, s2), t1 = csub(s0, s2);
            float2 t2 = cadd(s1, s3), t3 = csub(s1, s3);
            float2 it3 = make_float2(-sgn * t3.y, sgn * t3.x);
            X0 = cadd(t0, t2); X4 = csub(t0, t2);
            X2 = cadd(t1, it3); X6 = csub(t1, it3);
        }
        {
            float2 e0 = d0;
            float2 e1 = make_float2(R2 * (d1.x - sgn * d1.y), R2 * (sgn * d1.x + d1.y));
            float2 e2 = make_float2(-sgn * d2.y, sgn * d2.x);
            float2 e3 = make_float2(-R2 * (d3.x + sgn * d3.y), R2 * (sgn * d3.x - d3.y));
            float2 t0 = cadd(e0, e2), t1 = csub(e0, e2);
            float2 t2 = cadd(e1, e3), t3 = csub(e1, e3);
            float2 it3 = make_float2(-sgn * t3.y, sgn * t3.x);
            X1 = cadd(t0, t2); X5 = csub(t0, t2);
            X3 = cadd(t1, it3); X7 = csub(t1, it3);
        }
        int ob = q + 8 * s * p;
        x[PADI(ob)] = X0;
        float2 XX[7] = {X1, X2, X3, X4, X5, X6, X7};
        #pragma unroll
        for (int k = 0; k < 7; k++) {
            float2 u = XX[k];
            x[PADI(ob + s * (k + 1))] = FWD ? cmulc(u, w[k]) : cmul(w[k], u);
        }
        __syncthreads();
        s <<= 3; ls += 3; fac <<= 3;
    }
    {
        float2 v[8];
        #pragma unroll
        for (int k = 0; k < 8; k++) v[k] = x[PADI(tid + 256 * k)];
        __syncthreads();
        #pragma unroll
        for (int h = 0; h < 2; h++) {
            float2 c0 = v[h], c1 = v[h + 2], c2 = v[h + 4], c3 = v[h + 6];
            float2 t0 = cadd(c0, c2), t1 = csub(c0, c2);
            float2 t2 = cadd(c1, c3), t3 = csub(c1, c3);
            float2 it3 = make_float2(-sgn * t3.y, sgn * t3.x);
            int base = tid + 256 * h;
            x[PADI(base)]        = cadd(t0, t2);
            x[PADI(base + 512)]  = cadd(t1, it3);
            x[PADI(base + 1024)] = csub(t0, t2);
            x[PADI(base + 1536)] = csub(t1, it3);
        }
        __syncthreads();
    }
}

// One block per (nc, frame): windowed 4096-pt rfft via packed 2048 complex FFT.
// Xb layout: merged N rows [4*TPN][KP], row = nc*TPN + fr.
__global__ __launch_bounds__(256) void k_stft(const float* __restrict__ audio,
        bf16_t* __restrict__ Xb, unsigned* __restrict__ ph,
        const float2* __restrict__ tw) {
    __shared__ float2 buf[2176];
    int blk = blockIdx.x;
    int nc = blk / NFRAMES;
    int fr = blk - nc * NFRAMES;
    const float* a = audio + (size_t)nc * T_AUDIO;
    int tid = threadIdx.x;
    int base = fr * HOP - PAD;
    #pragma unroll
    for (int it = 0; it < 8; it++) {
        int m = tid + it * 256;
        int r0 = base + 2 * m;
        int r1 = r0 + 1;
        r0 = r0 < 0 ? -r0 : (r0 >= T_AUDIO ? 2 * T_AUDIO - 2 - r0 : r0);
        r1 = r1 < 0 ? -r1 : (r1 >= T_AUDIO ? 2 * T_AUDIO - 2 - r1 : r1);
        float4 tt = ((const float4*)tw)[m];
        float x0 = a[r0] * (0.5f - 0.5f * tt.x);
        float x1 = a[r1] * (0.5f - 0.5f * tt.z);
        buf[PADI(m)] = make_float2(x0, x1);
    }
    __syncthreads();
    fft2048_reg8<true>(buf, tid, tw);
    size_t orow = ((size_t)nc * NFRAMES + fr) * KP;
    bf16_t* Xrow = Xb + ((size_t)nc * TPN + fr) * KP;
    for (int k = tid; k < NBINS; k += 256) {
        float2 Zk = buf[PADI(k & 2047)];
        float2 Zm = buf[PADI((2048 - k) & 2047)];
        float ex = 0.5f * (Zk.x + Zm.x), ey = 0.5f * (Zk.y - Zm.y);
        float ox = 0.5f * (Zk.y + Zm.y), oy = -0.5f * (Zk.x - Zm.x);
        float2 w = tw[k];
        float re = ex + w.x * ox + w.y * oy;
        float im = ey + w.x * oy - w.y * ox;
        float mag = sqrtf(re * re + im * im);
        float inv = 1.0f / (mag + 1e-10f);
        Xrow[k] = (bf16_t)mag;
        ph[orow + k] = pack_bf2(re * inv, im * inv);
    }
}

// W fp32 -> Wb bf16 zero-padded; blocks 0..15 also fill the twiddle table.
__global__ __launch_bounds__(256) void k_convW(const float* __restrict__ W,
        bf16_t* __restrict__ Wb, float2* __restrict__ tw) {
    if (blockIdx.x < 16) {
        int i = blockIdx.x * 256 + threadIdx.x;
        float s, c;
        sincosf((float)i * (TWO_PI / 4096.0f), &s, &c);
        tw[i] = make_float2(c, s);
    }
    size_t idx = (size_t)blockIdx.x * 256 + threadIdx.x;
    size_t total = (size_t)4 * GP * KP / 8;
    if (idx >= total) return;
    size_t e = idx * 8;
    int f0 = (int)(e % KP);
    size_t rem = e / KP;
    int g = (int)(rem % GP);
    int j = (int)(rem / GP);
    bf16x8 v = {};
    if (g < NBINS) {
        const float* src = W + ((size_t)j * NBINS + g) * NBINS;
        #pragma unroll
        for (int r = 0; r < 8; r++) {
            int f = f0 + r;
            v[r] = (bf16_t)(f < NBINS ? src[f] : 0.0f);
        }
    }
    *(bf16x8*)(Wb + e) = v;
}

// V[jnc][t][g] = relu(sum_f W[j][g][f]*X[nc][t][f] + b[j][g]), bf16 out.
// BM=128, BN=128 (merged N=1792), BK=64; swizzled LDS (0 conflicts);
// XCD-grouped 1D grid (72 groups x 14 N-blocks).
__global__ __launch_bounds__(256) void k_gemm_mfma(const bf16_t* __restrict__ Wb,
        const float* __restrict__ bias, const bf16_t* __restrict__ Xb,
        bf16_t* __restrict__ V) {
    __shared__ bf16_t As[128 * 64];   // 16 KB
    __shared__ bf16_t Bs[128 * 64];   // 16 KB
    int id = blockIdx.x;
    int xcd = id & 7, nn = id >> 3;
    int G = xcd + 8 * (nn / 14);      // group = (j,g0); G%8 == xcd
    if (G >= 68) return;              // 72-group padding
    int mblk = nn % 14;
    int j  = G / 17;
    int g0 = (G % 17) * 128;
    int t0 = mblk * 128;              // merged N coordinate
    const bf16_t* A = Wb + ((size_t)j * GP + g0) * KP;
    const bf16_t* B = Xb + (size_t)t0 * KP;
    int tid = threadIdx.x;
    int lane = tid & 63, wid = tid >> 6;
    int wm = wid >> 1, wn = wid & 1;

    // staging: slot s holds 16B block (r = s>>3, c = (s&7) ^ (r&7))
    const bf16_t* srcA[4];
    const bf16_t* srcB[4];
    #pragma unroll
    for (int i = 0; i < 4; i++) {
        int s = i * 256 + tid;
        int r = s >> 3, cc = (s & 7) ^ (r & 7);
        srcA[i] = A + (size_t)r * KP + cc * 8;
        srcB[i] = B + (size_t)r * KP + cc * 8;
    }

    int laneLo = lane & 15, laneHi = lane >> 4;
    int offA[4][2], offB[4][2];
    #pragma unroll
    for (int mm = 0; mm < 4; mm++) {
        int r = wm * 64 + mm * 16 + laneLo;
        #pragma unroll
        for (int kk = 0; kk < 2; kk++) {
            int c = kk * 4 + laneHi;
            offA[mm][kk] = r * 128 + ((c ^ (r & 7)) << 4);
        }
    }
    #pragma unroll
    for (int n = 0; n < 4; n++) {
        int r = wn * 64 + n * 16 + laneLo;
        #pragma unroll
        for (int kk = 0; kk < 2; kk++) {
            int c = kk * 4 + laneHi;
            offB[n][kk] = r * 128 + ((c ^ (r & 7)) << 4);
        }
    }

    f32x4 acc[4][4];
    #pragma unroll
    for (int mm = 0; mm < 4; mm++)
        #pragma unroll
        for (int n = 0; n < 4; n++)
            acc[mm][n] = (f32x4){0.f, 0.f, 0.f, 0.f};

    for (int k0 = 0; k0 < KP; k0 += 64) {
        #pragma unroll
        for (int i = 0; i < 4; i++)
            __builtin_amdgcn_global_load_lds(
                (const __attribute__((address_space(1))) void*)(srcA[i] + k0),
                (__attribute__((address_space(3))) void*)(As + (i * 256 + tid) * 8),
                16, 0, 0);
        #pragma unroll
        for (int i = 0; i < 4; i++)
            __builtin_amdgcn_global_load_lds(
                (const __attribute__((address_space(1))) void*)(srcB[i] + k0),
                (__attribute__((address_space(3))) void*)(Bs + (i * 256 + tid) * 8),
                16, 0, 0);
        __syncthreads();

        #pragma unroll
        for (int kk = 0; kk < 2; kk++) {
            bf16x8 af[4], bfr[4];
            #pragma unroll
            for (int mm = 0; mm < 4; mm++)
                af[mm] = *(const bf16x8*)((const char*)As + offA[mm][kk]);
            #pragma unroll
            for (int n = 0; n < 4; n++)
                bfr[n] = *(const bf16x8*)((const char*)Bs + offB[n][kk]);
            #pragma unroll
            for (int mm = 0; mm < 4; mm++)
                #pragma unroll
                for (int n = 0; n < 4; n++)
                    acc[mm][n] = __builtin_amdgcn_mfma_f32_16x16x32_bf16(
                        af[mm], bfr[n], acc[mm][n], 0, 0, 0);
        }
        __syncthreads();
    }

    int colT = laneLo;
    int rowB = laneHi * 4;
    #pragma unroll
    for (int n = 0; n < 4; n++) {
        int t = t0 + wn * 64 + n * 16 + colT;   // merged N coord
        int nc = t / TPN;
        int tl = t - nc * TPN;
        if (tl >= NFRAMES) continue;
        size_t vrow = (((size_t)(j * 4 + nc)) * NFRAMES + tl) * KP;
        #pragma unroll
        for (int mm = 0; mm < 4; mm++) {
            int g = g0 + wm * 64 + mm * 16 + rowB;
            if (g + 3 < NBINS) {
                bf16x4 o;
                #pragma unroll
                for (int r = 0; r < 4; r++)
                    o[r] = (bf16_t)fmaxf(acc[mm][n][r] + bias[j * NBINS + g + r], 0.0f);
                *(bf16x4*)(V + vrow + g) = o;
            } else {
                #pragma unroll
                for (int r = 0; r < 4; r++) {
                    int gg = g + r;
                    if (gg < NBINS)
                        V[vrow + gg] = (bf16_t)fmaxf(acc[mm][n][r] + bias[j * NBINS + gg], 0.0f);
                }
            }
        }
    }
}

// One block per (njc, 4 frames): z-build direct from global V*phase, in-place
// iFFT, window+OLA into LDS accS, fp16 strip out.
__global__ __launch_bounds__(256) void k_istft(const bf16_t* __restrict__ V,
        const unsigned* __restrict__ ph, const float2* __restrict__ tw,
        h16* __restrict__ strips) {
    __shared__ float2 buf[2176];
    __shared__ float accS[SPAN];
    int b = blockIdx.x, njc = blockIdx.y;
    int n = njc >> 3, j = (njc >> 1) & 3, c = njc & 1;
    int nc = n * 2 + c;
    int jnc = j * 4 + nc;
    int tid = threadIdx.x;
    #pragma unroll
    for (int i = tid; i < SPAN / 4; i += 256)
        ((float4*)accS)[i] = make_float4(0.f, 0.f, 0.f, 0.f);

    for (int p = 0; p < 4; p++) {
        int fr = b * 4 + p;
        if (fr >= NFRAMES) break;
        size_t vrow = ((size_t)jnc * NFRAMES + fr) * KP;
        size_t prow = ((size_t)nc * NFRAMES + fr) * KP;
        #pragma unroll
        for (int it = 0; it < 8; it++) {
            int k = tid + it * 256;
            int km = 2048 - k;
            float vk = (float)V[vrow + k];
            float2 pk = unpack_bf2(ph[prow + k]);
            float vm = (float)V[vrow + km];
            float2 pm = unpack_bf2(ph[prow + km]);
            float2 Yk = make_float2(vk * pk.x, vk * pk.y);
            float2 Ym = make_float2(vm * pm.x, vm * pm.y);
            float ex = 0.5f * (Yk.x + Ym.x), ey = 0.5f * (Yk.y - Ym.y);
            float wx = 0.5f * (Yk.x - Ym.x), wy = 0.5f * (Yk.y + Ym.y);
            float2 w = tw[k];
            float ox_ = w.x * wx - w.y * wy;
            float oy_ = w.x * wy + w.y * wx;
            buf[PADI(k)] = make_float2(ex - oy_, ey + ox_);
        }
        __syncthreads();
        fft2048_reg8<false>(buf, tid, tw);
        const float scale = 1.0f / 2048.0f;
        #pragma unroll
        for (int it = 0; it < 8; it++) {
            int m = tid + it * 256;
            float2 z = buf[PADI(m)];
            float4 tt = ((const float4*)tw)[m];
            int o = p * 1024 + 2 * m;
            accS[o]     += z.x * scale * (0.5f - 0.5f * tt.x);
            accS[o + 1] += z.y * scale * (0.5f - 0.5f * tt.z);
        }
        __syncthreads();
    }
    h16* dst = strips + ((size_t)njc * NBLK + b) * SPAN;
    for (int i = tid; i < SPAN / 4; i += 256) {
        float4 v = ((float4*)accS)[i];
        h16x4 o = { (h16)v.x, (h16)v.y, (h16)v.z, (h16)v.w };
        *(h16x4*)(dst + i * 4) = o;
    }
}

// out[njc][t] = (strip[b1][o1] + strip[b1-1][o1+4096]) / wsq
__global__ __launch_bounds__(256) void k_final(const h16* __restrict__ strips,
        const float2* __restrict__ tw, float* __restrict__ out) {
    int gidx = blockIdx.x * 256 + threadIdx.x;
    int t = gidx * 2;
    if (t >= T_AUDIO) return;
    int njc = blockIdx.y;
    const h16* S = strips + (size_t)njc * NBLK * SPAN;
    float o[2];
    #pragma unroll
    for (int u = 0; u < 2; u++) {
        int tt = t + u;
        int q = tt + PAD;
        int b1 = q >> 12, o1 = q & 4095;
        float s = 0.f;
        if (b1 < NBLK) s += (float)S[b1 * SPAN + o1];
        if (b1 > 0 && o1 < SPAN - 4096) s += (float)S[(b1 - 1) * SPAN + o1 + 4096];
        float wsq;
        if (tt >= 1024 && tt <= 439295) {
            wsq = 1.5f;
        } else {
            wsq = 0.f;
            int ib = q >> 10;
            #pragma unroll
            for (int d = 0; d < 4; d++) {
                int i = ib - d;
                if (i >= 0 && i < NFRAMES) {
                    int m = q - (i << 10);
                    float w = 0.5f - 0.5f * tw[m].x;
                    wsq += w * w;
                }
            }
            if (!(wsq > 1e-11f)) wsq = 1.f;
        }
        o[u] = s / wsq;
    }
    *(float2*)(out + (size_t)njc * T_AUDIO + t) = make_float2(o[0], o[1]);
}

extern "C" void kernel_launch(void* const* d_in, const int* in_sizes, int n_in,
                              void* d_out, int out_size, void* d_ws, size_t ws_size,
                              hipStream_t stream) {
    const float* audio = (const float*)d_in[0];
    const float* Wm    = (const float*)d_in[1];
    const float* bias  = (const float*)d_in[2];
    float* out = (float*)d_out;
    char* ws = (char*)d_ws;

    size_t szWb  = (size_t)4 * GP * KP * sizeof(bf16_t);
    size_t szXb  = (size_t)4 * TPN * KP * sizeof(bf16_t);
    size_t szPh  = (size_t)4 * NFRAMES * KP * sizeof(unsigned);
    size_t szV   = (size_t)16 * NFRAMES * KP * sizeof(bf16_t);
    size_t szStr = (size_t)16 * NBLK * SPAN * sizeof(h16);
    size_t szTw  = (size_t)4096 * sizeof(float2);

    bf16_t*   Wb    = (bf16_t*)ws;   ws += szWb;
    bf16_t*   Xb    = (bf16_t*)ws;   ws += szXb;
    unsigned* ph    = (unsigned*)ws; ws += szPh;
    bf16_t*   V     = (bf16_t*)ws;   ws += szV;
    h16*      strips= (h16*)ws;      ws += szStr;
    float2*   tw    = (float2*)ws;   ws += szTw;
    if ((size_t)(ws - (char*)d_ws) > ws_size) return;

    hipMemsetAsync(Xb, 0, szXb, stream);

    k_convW<<<dim3((unsigned)((4ull * GP * KP / 8 + 255) / 256)), 256, 0, stream>>>(Wm, Wb, tw);
    k_stft<<<dim3(4 * NFRAMES), 256, 0, stream>>>(audio, Xb, ph, tw);
    k_gemm_mfma<<<dim3(72 * 14), 256, 0, stream>>>(Wb, bias, Xb, V);
    k_istft<<<dim3(NBLK, 16), 256, 0, stream>>>(V, ph, tw, strips);
    k_final<<<dim3((T_AUDIO / 2 + 255) / 256, 16), 256, 0, stream>>>(strips, tw, out);
}

// Round 7
// 243.868 us; speedup vs baseline: 1.2851x; 1.0462x over previous
//
#include <hip/hip_runtime.h>
#include <hip/hip_bf16.h>
#include <math.h>

#define T_AUDIO 441000
#define NH   2048
#define HOP  1024
#define NBINS 2049
#define NFRAMES 431
#define PAD  2048

// GEMM padded dims (bf16 buffers, zero-filled padding -> no guards in GEMM)
#define GP  2176   // padded g (M) = 17*128
#define KP  2112   // padded f (K) = 33*64
#define TPN 448    // padded frames per nc (7*64)

#define NBLK 108   // istft blocks per njc (4 frames each)
#define SPAN 7168  // 4096 + 3*1024 samples per istft block

#define TWO_PI 6.2831853071795864769f

// LDS index padding for FFT buffers: +1 float2 per 16
#define PADI(i) ((i) + ((i) >> 4))

typedef __bf16 bf16_t;
typedef bf16_t bf16x8 __attribute__((ext_vector_type(8)));
typedef bf16_t bf16x4 __attribute__((ext_vector_type(4)));
typedef float f32x4 __attribute__((ext_vector_type(4)));
typedef _Float16 h16;
typedef h16 h16x2 __attribute__((ext_vector_type(2)));

__device__ __forceinline__ unsigned pack_bf2(float a, float b) {
    union { bf16_t h; unsigned short u; } ca, cb;
    ca.h = (bf16_t)a; cb.h = (bf16_t)b;
    return (unsigned)ca.u | ((unsigned)cb.u << 16);
}
__device__ __forceinline__ float2 unpack_bf2(unsigned v) {
    union { unsigned u; float f; } a, b;
    a.u = v << 16;
    b.u = v & 0xffff0000u;
    return make_float2(a.f, b.f);
}

__device__ __forceinline__ float2 cadd(float2 a, float2 b) { return make_float2(a.x + b.x, a.y + b.y); }
__device__ __forceinline__ float2 csub(float2 a, float2 b) { return make_float2(a.x - b.x, a.y - b.y); }
__device__ __forceinline__ float2 cmul(float2 a, float2 b) {       // a*b
    return make_float2(a.x * b.x - a.y * b.y, a.x * b.y + a.y * b.x);
}
__device__ __forceinline__ float2 cmulc(float2 u, float2 w) {      // u*conj(w)
    return make_float2(u.x * w.x + u.y * w.y, u.y * w.x - u.x * w.y);
}

// In-place Stockham FFT len 2048 in ONE LDS buffer: 3 radix-8 register sweeps
// + 1 dual radix-4 sweep. 256 threads; loads always x[PADI(tid+256k)] (each
// thread's OWN slots). Ends with a barrier; result in natural order.
template<bool FWD>
__device__ __forceinline__ void fft2048_reg8(float2* x, int tid,
                                             const float2* __restrict__ tw) {
    const float sgn = FWD ? -1.0f : 1.0f;
    const float R2 = 0.70710678118654752440f;
    int s = 1, ls = 0, fac = 2;
    #pragma unroll
    for (int st = 0; st < 3; st++) {
        int q = tid & (s - 1);
        int p = tid >> ls;
        int e = p * fac;
        float2 w[7];
        #pragma unroll
        for (int k = 0; k < 7; k++) w[k] = tw[e * (k + 1)];
        float2 v[8];
        #pragma unroll
        for (int k = 0; k < 8; k++) v[k] = x[PADI(tid + 256 * k)];
        __syncthreads();
        float2 s0 = cadd(v[0], v[4]), s1 = cadd(v[1], v[5]),
               s2 = cadd(v[2], v[6]), s3 = cadd(v[3], v[7]);
        float2 d0 = csub(v[0], v[4]), d1 = csub(v[1], v[5]),
               d2 = csub(v[2], v[6]), d3 = csub(v[3], v[7]);
        float2 X0, X1, X2, X3, X4, X5, X6, X7;
        {
            float2 t0 = cadd(s0, s2), t1 = csub(s0, s2);
            float2 t2 = cadd(s1, s3), t3 = csub(s1, s3);
            float2 it3 = make_float2(-sgn * t3.y, sgn * t3.x);
            X0 = cadd(t0, t2); X4 = csub(t0, t2);
            X2 = cadd(t1, it3); X6 = csub(t1, it3);
        }
        {
            float2 e0 = d0;
            float2 e1 = make_float2(R2 * (d1.x - sgn * d1.y), R2 * (sgn * d1.x + d1.y));
            float2 e2 = make_float2(-sgn * d2.y, sgn * d2.x);
            float2 e3 = make_float2(-R2 * (d3.x + sgn * d3.y), R2 * (sgn * d3.x - d3.y));
            float2 t0 = cadd(e0, e2), t1 = csub(e0, e2);
            float2 t2 = cadd(e1, e3), t3 = csub(e1, e3);
            float2 it3 = make_float2(-sgn * t3.y, sgn * t3.x);
            X1 = cadd(t0, t2); X5 = csub(t0, t2);
            X3 = cadd(t1, it3); X7 = csub(t1, it3);
        }
        int ob = q + 8 * s * p;
        x[PADI(ob)] = X0;
        float2 XX[7] = {X1, X2, X3, X4, X5, X6, X7};
        #pragma unroll
        for (int k = 0; k < 7; k++) {
            float2 u = XX[k];
            x[PADI(ob + s * (k + 1))] = FWD ? cmulc(u, w[k]) : cmul(w[k], u);
        }
        __syncthreads();
        s <<= 3; ls += 3; fac <<= 3;
    }
    {
        float2 v[8];
        #pragma unroll
        for (int k = 0; k < 8; k++) v[k] = x[PADI(tid + 256 * k)];
        __syncthreads();
        #pragma unroll
        for (int h = 0; h < 2; h++) {
            float2 c0 = v[h], c1 = v[h + 2], c2 = v[h + 4], c3 = v[h + 6];
            float2 t0 = cadd(c0, c2), t1 = csub(c0, c2);
            float2 t2 = cadd(c1, c3), t3 = csub(c1, c3);
            float2 it3 = make_float2(-sgn * t3.y, sgn * t3.x);
            int base = tid + 256 * h;
            x[PADI(base)]        = cadd(t0, t2);
            x[PADI(base + 512)]  = cadd(t1, it3);
            x[PADI(base + 1024)] = csub(t0, t2);
            x[PADI(base + 1536)] = csub(t1, it3);
        }
        __syncthreads();
    }
}

// One block per (nc, frame): windowed 4096-pt rfft via packed 2048 complex FFT.
__global__ __launch_bounds__(256) void k_stft(const float* __restrict__ audio,
        bf16_t* __restrict__ Xb, unsigned* __restrict__ ph,
        const float2* __restrict__ tw) {
    __shared__ float2 buf[2176];
    int blk = blockIdx.x;
    int nc = blk / NFRAMES;
    int fr = blk - nc * NFRAMES;
    const float* a = audio + (size_t)nc * T_AUDIO;
    int tid = threadIdx.x;
    int base = fr * HOP - PAD;
    #pragma unroll
    for (int it = 0; it < 8; it++) {
        int m = tid + it * 256;     // own slots -> no barrier needed before FFT
        int r0 = base + 2 * m;
        int r1 = r0 + 1;
        r0 = r0 < 0 ? -r0 : (r0 >= T_AUDIO ? 2 * T_AUDIO - 2 - r0 : r0);
        r1 = r1 < 0 ? -r1 : (r1 >= T_AUDIO ? 2 * T_AUDIO - 2 - r1 : r1);
        float4 tt = ((const float4*)tw)[m];
        float x0 = a[r0] * (0.5f - 0.5f * tt.x);
        float x1 = a[r1] * (0.5f - 0.5f * tt.z);
        buf[PADI(m)] = make_float2(x0, x1);
    }
    fft2048_reg8<true>(buf, tid, tw);
    size_t orow = ((size_t)nc * NFRAMES + fr) * KP;
    bf16_t* Xrow = Xb + ((size_t)nc * TPN + fr) * KP;
    for (int k = tid; k < NBINS; k += 256) {
        float2 Zk = buf[PADI(k & 2047)];
        float2 Zm = buf[PADI((2048 - k) & 2047)];
        float ex = 0.5f * (Zk.x + Zm.x), ey = 0.5f * (Zk.y - Zm.y);
        float ox = 0.5f * (Zk.y + Zm.y), oy = -0.5f * (Zk.x - Zm.x);
        float2 w = tw[k];
        float re = ex + w.x * ox + w.y * oy;
        float im = ey + w.x * oy - w.y * ox;
        float mag = sqrtf(re * re + im * im);
        float inv = 1.0f / (mag + 1e-10f);
        Xrow[k] = (bf16_t)mag;
        ph[orow + k] = pack_bf2(re * inv, im * inv);
    }
}

// W fp32 -> Wb bf16 zero-padded; blocks 0..15 also fill the twiddle table.
__global__ __launch_bounds__(256) void k_convW(const float* __restrict__ W,
        bf16_t* __restrict__ Wb, float2* __restrict__ tw) {
    if (blockIdx.x < 16) {
        int i = blockIdx.x * 256 + threadIdx.x;
        float s, c;
        sincosf((float)i * (TWO_PI / 4096.0f), &s, &c);
        tw[i] = make_float2(c, s);
    }
    size_t idx = (size_t)blockIdx.x * 256 + threadIdx.x;
    size_t total = (size_t)4 * GP * KP / 8;
    if (idx >= total) return;
    size_t e = idx * 8;
    int f0 = (int)(e % KP);
    size_t rem = e / KP;
    int g = (int)(rem % GP);
    int j = (int)(rem / GP);
    bf16x8 v = {};
    if (g < NBINS) {
        const float* src = W + ((size_t)j * NBINS + g) * NBINS;
        #pragma unroll
        for (int r = 0; r < 8; r++) {
            int f = f0 + r;
            v[r] = (bf16_t)(f < NBINS ? src[f] : 0.0f);
        }
    }
    *(bf16x8*)(Wb + e) = v;
}

// V[jnc][t][g] = relu(sum_f W[j][g][f]*X[nc][t][f] + b[j][g]), bf16 out.
// Proven r5 shape: BM=128, BN=64, BK=64; swizzled LDS (0 conflicts);
// XCD-grouped 1D grid (72 groups x 28 N-blocks = 2016, 1904 real).
__global__ __launch_bounds__(256) void k_gemm_mfma(const bf16_t* __restrict__ Wb,
        const float* __restrict__ bias, const bf16_t* __restrict__ Xb,
        bf16_t* __restrict__ V) {
    __shared__ bf16_t As[128 * 64];   // 16 KB
    __shared__ bf16_t Bs[64 * 64];    // 8 KB
    int id = blockIdx.x;
    int xcd = id & 7, nn = id >> 3;
    int G = xcd + 8 * (nn / 28);      // group = (j,g0); G%8 == xcd
    if (G >= 68) return;              // 72-group padding
    int m28 = nn % 28;
    int j  = G / 17;
    int g0 = (G % 17) * 128;
    int nc = m28 / 7;
    int t0 = (m28 % 7) * 64;
    const bf16_t* A = Wb + ((size_t)j * GP + g0) * KP;
    const bf16_t* B = Xb + ((size_t)nc * TPN + t0) * KP;
    int tid = threadIdx.x;
    int lane = tid & 63, wid = tid >> 6;
    int wm = wid >> 1, wn = wid & 1;

    const bf16_t* srcA[4];
    #pragma unroll
    for (int i = 0; i < 4; i++) {
        int s = i * 256 + tid;
        int r = s >> 3, cc = (s & 7) ^ (r & 7);
        srcA[i] = A + (size_t)r * KP + cc * 8;
    }
    const bf16_t* srcB[2];
    #pragma unroll
    for (int i = 0; i < 2; i++) {
        int s = i * 256 + tid;
        int r = s >> 3, cc = (s & 7) ^ (r & 7);
        srcB[i] = B + (size_t)r * KP + cc * 8;
    }

    int laneLo = lane & 15, laneHi = lane >> 4;
    int offA[4][2], offB[2][2];
    #pragma unroll
    for (int mm = 0; mm < 4; mm++) {
        int r = wm * 64 + mm * 16 + laneLo;
        #pragma unroll
        for (int kk = 0; kk < 2; kk++) {
            int c = kk * 4 + laneHi;
            offA[mm][kk] = r * 128 + ((c ^ (r & 7)) << 4);
        }
    }
    #pragma unroll
    for (int n = 0; n < 2; n++) {
        int r = wn * 32 + n * 16 + laneLo;
        #pragma unroll
        for (int kk = 0; kk < 2; kk++) {
            int c = kk * 4 + laneHi;
            offB[n][kk] = r * 128 + ((c ^ (r & 7)) << 4);
        }
    }

    f32x4 acc[4][2];
    #pragma unroll
    for (int mm = 0; mm < 4; mm++)
        #pragma unroll
        for (int n = 0; n < 2; n++)
            acc[mm][n] = (f32x4){0.f, 0.f, 0.f, 0.f};

    for (int k0 = 0; k0 < KP; k0 += 64) {
        #pragma unroll
        for (int i = 0; i < 4; i++)
            __builtin_amdgcn_global_load_lds(
                (const __attribute__((address_space(1))) void*)(srcA[i] + k0),
                (__attribute__((address_space(3))) void*)(As + (i * 256 + tid) * 8),
                16, 0, 0);
        #pragma unroll
        for (int i = 0; i < 2; i++)
            __builtin_amdgcn_global_load_lds(
                (const __attribute__((address_space(1))) void*)(srcB[i] + k0),
                (__attribute__((address_space(3))) void*)(Bs + (i * 256 + tid) * 8),
                16, 0, 0);
        __syncthreads();

        bf16x8 af[4][2], bfr[2][2];
        #pragma unroll
        for (int mm = 0; mm < 4; mm++)
            #pragma unroll
            for (int kk = 0; kk < 2; kk++)
                af[mm][kk] = *(const bf16x8*)((const char*)As + offA[mm][kk]);
        #pragma unroll
        for (int n = 0; n < 2; n++)
            #pragma unroll
            for (int kk = 0; kk < 2; kk++)
                bfr[n][kk] = *(const bf16x8*)((const char*)Bs + offB[n][kk]);
        #pragma unroll
        for (int mm = 0; mm < 4; mm++)
            #pragma unroll
            for (int n = 0; n < 2; n++)
                #pragma unroll
                for (int kk = 0; kk < 2; kk++)
                    acc[mm][n] = __builtin_amdgcn_mfma_f32_16x16x32_bf16(
                        af[mm][kk], bfr[n][kk], acc[mm][n], 0, 0, 0);
        __syncthreads();
    }

    int jnc = j * 4 + nc;
    int colT = laneLo;
    int rowB = laneHi * 4;
    #pragma unroll
    for (int n = 0; n < 2; n++) {
        int t = t0 + wn * 32 + n * 16 + colT;
        if (t >= NFRAMES) continue;
        size_t vrow = ((size_t)jnc * NFRAMES + t) * KP;
        #pragma unroll
        for (int mm = 0; mm < 4; mm++) {
            int g = g0 + wm * 64 + mm * 16 + rowB;
            if (g + 3 < NBINS) {
                bf16x4 o;
                #pragma unroll
                for (int r = 0; r < 4; r++)
                    o[r] = (bf16_t)fmaxf(acc[mm][n][r] + bias[j * NBINS + g + r], 0.0f);
                *(bf16x4*)(V + vrow + g) = o;
            } else {
                #pragma unroll
                for (int r = 0; r < 4; r++) {
                    int gg = g + r;
                    if (gg < NBINS)
                        V[vrow + gg] = (bf16_t)fmaxf(acc[mm][n][r] + bias[j * NBINS + gg], 0.0f);
                }
            }
        }
    }
}

// One block per (njc, 4 frames). OLA lives in REGISTERS: thread tid owns strip
// slots 512u + 2*tid + {0,1}, u = 2p+it in [0,14). Only 17.4KB LDS (FFT buf).
__global__ __launch_bounds__(256) void k_istft(const bf16_t* __restrict__ V,
        const unsigned* __restrict__ ph, const float2* __restrict__ tw,
        h16* __restrict__ strips) {
    __shared__ float2 buf[2176];
    int b = blockIdx.x, njc = blockIdx.y;
    int n = njc >> 3, j = (njc >> 1) & 3, c = njc & 1;
    int nc = n * 2 + c;
    int jnc = j * 4 + nc;
    int tid = threadIdx.x;
    const float scale = 1.0f / 2048.0f;
    float2 acc[14];
    #pragma unroll
    for (int u = 0; u < 14; u++) acc[u] = make_float2(0.f, 0.f);

    #pragma unroll
    for (int p = 0; p < 4; p++) {
        int fr = b * 4 + p;
        if (fr < NFRAMES) {   // block-uniform guard
            size_t vrow = ((size_t)jnc * NFRAMES + fr) * KP;
            size_t prow = ((size_t)nc * NFRAMES + fr) * KP;
            // z-build writes only thread-own slots -> no barrier needed;
            // the FFT's internal barrier (after own-slot loads) orders it.
            #pragma unroll
            for (int it = 0; it < 8; it++) {
                int k = tid + it * 256;
                int km = 2048 - k;
                float vk = (float)V[vrow + k];
                float2 pk = unpack_bf2(ph[prow + k]);
                float vm = (float)V[vrow + km];
                float2 pm = unpack_bf2(ph[prow + km]);
                float2 Yk = make_float2(vk * pk.x, vk * pk.y);
                float2 Ym = make_float2(vm * pm.x, vm * pm.y);
                float ex = 0.5f * (Yk.x + Ym.x), ey = 0.5f * (Yk.y - Ym.y);
                float wx = 0.5f * (Yk.x - Ym.x), wy = 0.5f * (Yk.y + Ym.y);
                float2 w = tw[k];
                float ox_ = w.x * wx - w.y * wy;
                float oy_ = w.x * wy + w.y * wx;
                buf[PADI(k)] = make_float2(ex - oy_, ey + ox_);
            }
            fft2048_reg8<false>(buf, tid, tw);
            // OLA into registers (reads only own slots) -> no trailing barrier
            #pragma unroll
            for (int it = 0; it < 8; it++) {
                int m = tid + it * 256;
                float2 z = buf[PADI(m)];
                float4 tt = ((const float4*)tw)[m];
                acc[2 * p + it].x += z.x * scale * (0.5f - 0.5f * tt.x);
                acc[2 * p + it].y += z.y * scale * (0.5f - 0.5f * tt.z);
            }
        }
    }
    h16* dst = strips + ((size_t)njc * NBLK + b) * SPAN;
    #pragma unroll
    for (int u = 0; u < 14; u++) {
        h16x2 o = { (h16)acc[u].x, (h16)acc[u].y };
        *(h16x2*)(dst + 512 * u + 2 * tid) = o;
    }
}

// out[njc][t] = (strip[b1][o1] + strip[b1-1][o1+4096]) / wsq
__global__ __launch_bounds__(256) void k_final(const h16* __restrict__ strips,
        const float2* __restrict__ tw, float* __restrict__ out) {
    int gidx = blockIdx.x * 256 + threadIdx.x;
    int t = gidx * 2;
    if (t >= T_AUDIO) return;
    int njc = blockIdx.y;
    const h16* S = strips + (size_t)njc * NBLK * SPAN;
    float o[2];
    #pragma unroll
    for (int u = 0; u < 2; u++) {
        int tt = t + u;
        int q = tt + PAD;
        int b1 = q >> 12, o1 = q & 4095;
        float s = 0.f;
        if (b1 < NBLK) s += (float)S[b1 * SPAN + o1];
        if (b1 > 0 && o1 < SPAN - 4096) s += (float)S[(b1 - 1) * SPAN + o1 + 4096];
        float wsq;
        if (tt >= 1024 && tt <= 439295) {
            wsq = 1.5f;
        } else {
            wsq = 0.f;
            int ib = q >> 10;
            #pragma unroll
            for (int d = 0; d < 4; d++) {
                int i = ib - d;
                if (i >= 0 && i < NFRAMES) {
                    int m = q - (i << 10);
                    float w = 0.5f - 0.5f * tw[m].x;
                    wsq += w * w;
                }
            }
            if (!(wsq > 1e-11f)) wsq = 1.f;
        }
        o[u] = s / wsq;
    }
    *(float2*)(out + (size_t)njc * T_AUDIO + t) = make_float2(o[0], o[1]);
}

extern "C" void kernel_launch(void* const* d_in, const int* in_sizes, int n_in,
                              void* d_out, int out_size, void* d_ws, size_t ws_size,
                              hipStream_t stream) {
    const float* audio = (const float*)d_in[0];
    const float* Wm    = (const float*)d_in[1];
    const float* bias  = (const float*)d_in[2];
    float* out = (float*)d_out;
    char* ws = (char*)d_ws;

    size_t szWb  = (size_t)4 * GP * KP * sizeof(bf16_t);
    size_t szXb  = (size_t)4 * TPN * KP * sizeof(bf16_t);
    size_t szPh  = (size_t)4 * NFRAMES * KP * sizeof(unsigned);
    size_t szV   = (size_t)16 * NFRAMES * KP * sizeof(bf16_t);
    size_t szStr = (size_t)16 * NBLK * SPAN * sizeof(h16);
    size_t szTw  = (size_t)4096 * sizeof(float2);

    bf16_t*   Wb    = (bf16_t*)ws;   ws += szWb;
    bf16_t*   Xb    = (bf16_t*)ws;   ws += szXb;
    unsigned* ph    = (unsigned*)ws; ws += szPh;
    bf16_t*   V     = (bf16_t*)ws;   ws += szV;
    h16*      strips= (h16*)ws;      ws += szStr;
    float2*   tw    = (float2*)ws;   ws += szTw;
    if ((size_t)(ws - (char*)d_ws) > ws_size) return;

    hipMemsetAsync(Xb, 0, szXb, stream);

    k_convW<<<dim3((unsigned)((4ull * GP * KP / 8 + 255) / 256)), 256, 0, stream>>>(Wm, Wb, tw);
    k_stft<<<dim3(4 * NFRAMES), 256, 0, stream>>>(audio, Xb, ph, tw);
    k_gemm_mfma<<<dim3(72 * 28), 256, 0, stream>>>(Wb, bias, Xb, V);
    k_istft<<<dim3(NBLK, 16), 256, 0, stream>>>(V, ph, tw, strips);
    k_final<<<dim3((T_AUDIO / 2 + 255) / 256, 16), 256, 0, stream>>>(strips, tw, out);
}